// Round 4
// baseline (845.380 us; speedup 1.0000x reference)
//
#include <hip/hip_runtime.h>

// ---------------------------------------------------------------------------
// DeepProteinClassifier: x[32,1024,960] fp32, mask[32,1024] i32 ->
//   QKV proj -> scores GEMM -> masked softmax -> PV GEMM -> +x,LN ->
//   masked mean pool -> MLP -> [32,10] f32
// All big GEMMs: 256x256 tile, 4-phase-per-K-tile counted-vmcnt schedule.
// ---------------------------------------------------------------------------

#define DEVINL __device__ __forceinline__

typedef __attribute__((ext_vector_type(8))) short bf16x8;
typedef __attribute__((ext_vector_type(4))) float f32x4;
typedef __attribute__((ext_vector_type(4))) unsigned short u16x4;

DEVINL unsigned short f2bf(float f) {
  unsigned int u = __float_as_uint(f);
  u += 0x7FFFu + ((u >> 16) & 1u);  // round-to-nearest-even
  return (unsigned short)(u >> 16);
}

DEVINL float bf2f(unsigned short h) {
  return __uint_as_float(((unsigned int)h) << 16);
}

DEVINL void gload_lds16(const void* g, void* l) {
  __builtin_amdgcn_global_load_lds((const __attribute__((address_space(1))) unsigned int*)g,
                                   (__attribute__((address_space(3))) unsigned int*)l,
                                   16, 0, 0);
}

#define MFMA16(a, b, c) __builtin_amdgcn_mfma_f32_16x16x32_bf16((a), (b), (c), 0, 0, 0)

// ---------------------------------------------------------------------------
// Build Wqkv [3072][1024] bf16 (rows 0..959 Wq*scale, 960..1919 Wk,
// 1920..2879 Wv; cols 960..1023 zero) and biasQKV[2880] f32.
// ---------------------------------------------------------------------------
__global__ __launch_bounds__(256) void cast_wqkv(
    const float* __restrict__ Wq, const float* __restrict__ Wk, const float* __restrict__ Wv,
    const float* __restrict__ bq, const float* __restrict__ bk, const float* __restrict__ bv,
    unsigned short* __restrict__ Wqkv, float* __restrict__ biasQ, float scaleQ) {
  const int r = blockIdx.x, t = threadIdx.x;
  const int seg = (r >= 1920) ? 2 : (r >= 960 ? 1 : 0);
  const int sr = r - seg * 960;
  const float* W = (seg == 0) ? Wq : (seg == 1) ? Wk : Wv;
  const float sc = (seg == 0) ? scaleQ : 1.0f;
  if (t < 240) {
    f32x4 v = *(const f32x4*)(W + (size_t)sr * 960 + t * 4);
    u16x4 o;
    o[0] = f2bf(v[0] * sc); o[1] = f2bf(v[1] * sc);
    o[2] = f2bf(v[2] * sc); o[3] = f2bf(v[3] * sc);
    *(u16x4*)(Wqkv + (size_t)r * 1024 + t * 4) = o;
  } else {
    u16x4 z = {};
    *(u16x4*)(Wqkv + (size_t)r * 1024 + 960 + (t - 240) * 4) = z;
  }
  if (t == 0) {
    const float* bb = (seg == 0) ? bq : (seg == 1) ? bk : bv;
    biasQ[r] = bb[sr] * sc;
  }
}

// ---------------------------------------------------------------------------
// cast x [32768][960] f32 -> xb [32768][1024] bf16 (cols 960.. zero).
// ---------------------------------------------------------------------------
__global__ __launch_bounds__(256) void cast_x(
    const float* __restrict__ x, unsigned short* __restrict__ xb) {
  const int row = blockIdx.x * 4 + (threadIdx.x >> 6);
  const int l = threadIdx.x & 63;
  unsigned short* o = xb + (size_t)row * 1024 + l * 16;
  if (l < 60) {
    const float* g = x + (size_t)row * 960 + l * 16;
    f32x4 v0 = *(const f32x4*)(g);
    f32x4 v1 = *(const f32x4*)(g + 4);
    f32x4 v2 = *(const f32x4*)(g + 8);
    f32x4 v3 = *(const f32x4*)(g + 12);
    bf16x8 o0, o1;
    o0[0] = (short)f2bf(v0[0]); o0[1] = (short)f2bf(v0[1]);
    o0[2] = (short)f2bf(v0[2]); o0[3] = (short)f2bf(v0[3]);
    o0[4] = (short)f2bf(v1[0]); o0[5] = (short)f2bf(v1[1]);
    o0[6] = (short)f2bf(v1[2]); o0[7] = (short)f2bf(v1[3]);
    o1[0] = (short)f2bf(v2[0]); o1[1] = (short)f2bf(v2[1]);
    o1[2] = (short)f2bf(v2[2]); o1[3] = (short)f2bf(v2[3]);
    o1[4] = (short)f2bf(v3[0]); o1[5] = (short)f2bf(v3[1]);
    o1[6] = (short)f2bf(v3[2]); o1[7] = (short)f2bf(v3[3]);
    *(bf16x8*)(o) = o0;
    *(bf16x8*)(o + 8) = o1;
  } else {
    bf16x8 z = {};
    *(bf16x8*)(o) = z;
    *(bf16x8*)(o + 8) = z;
  }
}

// ---------------------------------------------------------------------------
// 256x256-tile NT GEMM, 4-phase-per-K-tile counted-vmcnt schedule.
// 8 waves (wr=w>>2 in {0,1}, wc=w&3), per-wave out 128x64, acc[8][4].
// LDS: As/Bs[2 dbuf][2 half][128*64] bf16 = 128 KB total.
// Per phase: stage one half-tile of K-tile kt+1 (2 gload_lds/thread),
//   (K-tile start: s_waitcnt vmcnt(2) -- never 0 mid-loop), s_barrier,
//   8x ds_read_b128, lgkmcnt(0)+sched_barrier, setprio(1) 16 MFMA setprio(0),
//   s_barrier. Source-side (row&7) XOR swizzle on 16B slots, LDS linear.
// MODE 0: f32 out (PV->ctx).  MODE 1: QKV epilogue (bf16 +bias -> Qb/Kb/VtT).
// MODE 3: bf16 raw batched out (scores -> S).
// XCD-chunked flat-grid swizzle (nwg % 8 == 0).
// ---------------------------------------------------------------------------
template <int MODE>
__global__ __launch_bounds__(512, 2) void gemm256(
    const unsigned short* __restrict__ Ap, const unsigned short* __restrict__ Bp,
    int lda, int ldb, const float* __restrict__ bias,
    float* __restrict__ outF, unsigned short* __restrict__ outB,
    unsigned short* __restrict__ outQ, unsigned short* __restrict__ outK,
    unsigned short* __restrict__ outV,
    int mTiles, int nTiles, int nkt, int ncols, int ldo,
    size_t aStride, size_t bStride, size_t oStride) {
  __shared__ unsigned short As[2][2][128 * 64];
  __shared__ unsigned short Bs[2][2][128 * 64];
  const int t = threadIdx.x, l = t & 63, w = t >> 6;
  const int wr = w >> 2, wc = w & 3;
  const int lq = l & 15, lh = l >> 4;

  const int nwg = (int)gridDim.x;
  const int flat = (int)blockIdx.x;
  const int swz = (flat & 7) * (nwg >> 3) + (flat >> 3);
  const int pt = mTiles * nTiles;
  const int zb = swz / pt;
  const int rm = swz - zb * pt;
  const int mi = rm / nTiles;
  const int m0 = mi * 256;
  const int n0 = (rm - mi * nTiles) * 256;

  const unsigned short* Ablk = Ap + (size_t)zb * aStride + (size_t)m0 * lda;
  const unsigned short* Bblk = Bp + (size_t)zb * bStride + (size_t)n0 * ldb;

  // stage one 128x64 half-tile: 2 gload_lds/thread; LDS linear, source swizzled
#define STAGEH(GBASE, LD, LDSBASE, D0)                                        \
  {                                                                           \
    _Pragma("unroll") for (int p_ = 0; p_ < 2; ++p_) {                        \
      const int r_ = p_ * 64 + w * 8 + (l >> 3);                              \
      const int sg_ = (l & 7) ^ (r_ & 7);                                     \
      gload_lds16((GBASE) + (size_t)r_ * (LD) + (D0) + sg_ * 8,               \
                  (char*)(LDSBASE) + (size_t)(p_ * 64 + w * 8) * 128);        \
    }                                                                         \
  }

  // one quadrant: (KK, IH); reads 4 aF + 4 bF, 16 MFMA
#define QUAD(KK, IH, ACUR, BCUR)                                              \
  {                                                                           \
    bf16x8 aF[4], bF[4];                                                      \
    _Pragma("unroll") for (int i_ = 0; i_ < 4; ++i_) {                        \
      const int r_ = ((IH) * 4 + i_) * 16 + lq;                               \
      aF[i_] = *(const bf16x8*)((ACUR) + (size_t)wr * 8192 + r_ * 64 +        \
                                ((((KK) << 2) | lh) ^ (r_ & 7)) * 8);         \
    }                                                                         \
    _Pragma("unroll") for (int j_ = 0; j_ < 4; ++j_) {                        \
      const int r_ = (wc & 1) * 64 + 16 * j_ + lq;                            \
      bF[j_] = *(const bf16x8*)((BCUR) + (size_t)(wc >> 1) * 8192 + r_ * 64 + \
                                ((((KK) << 2) | lh) ^ (r_ & 7)) * 8);         \
    }                                                                         \
    asm volatile("s_waitcnt lgkmcnt(0)" ::: "memory");                        \
    __builtin_amdgcn_sched_barrier(0);                                        \
    __builtin_amdgcn_s_setprio(1);                                            \
    _Pragma("unroll") for (int i_ = 0; i_ < 4; ++i_)                          \
      _Pragma("unroll") for (int j_ = 0; j_ < 4; ++j_)                        \
        acc[(IH) * 4 + i_][j_] = MFMA16(aF[i_], bF[j_], acc[(IH) * 4 + i_][j_]); \
    __builtin_amdgcn_s_setprio(0);                                            \
  }

  f32x4 acc[8][4] = {};

  // prologue: stage K-tile 0 fully into slot 0 (8 loads/thread)
  STAGEH(Ablk, lda, &As[0][0][0], 0);
  STAGEH(Ablk + (size_t)128 * lda, lda, &As[0][1][0], 0);
  STAGEH(Bblk, ldb, &Bs[0][0][0], 0);
  STAGEH(Bblk + (size_t)128 * ldb, ldb, &Bs[0][1][0], 0);

  for (int kt = 0; kt < nkt; ++kt) {
    const int slot = kt & 1;
    unsigned short* Acur = &As[slot][0][0];
    unsigned short* Bcur = &Bs[slot][0][0];
    unsigned short* Anx = &As[slot ^ 1][0][0];
    unsigned short* Bnx = &Bs[slot ^ 1][0][0];
    const int d0n = (kt + 1) * 64;
    const bool more = (kt + 1 < nkt);

    // ---- phase 0: quadrant (kk0, ih0); stage A-half0 of kt+1
    if (more) STAGEH(Ablk, lda, Anx, d0n);
    if (more) { asm volatile("s_waitcnt vmcnt(2)" ::: "memory"); }
    else      { asm volatile("s_waitcnt vmcnt(0)" ::: "memory"); }
    __builtin_amdgcn_sched_barrier(0);
    __builtin_amdgcn_s_barrier();
    __builtin_amdgcn_sched_barrier(0);
    QUAD(0, 0, Acur, Bcur);
    __builtin_amdgcn_s_barrier();
    // ---- phase 1: quadrant (kk0, ih1); stage A-half1
    if (more) STAGEH(Ablk + (size_t)128 * lda, lda, Anx + 8192, d0n);
    QUAD(0, 1, Acur, Bcur);
    __builtin_amdgcn_s_barrier();
    // ---- phase 2: quadrant (kk1, ih0); stage B-half0
    if (more) STAGEH(Bblk, ldb, Bnx, d0n);
    QUAD(1, 0, Acur, Bcur);
    __builtin_amdgcn_s_barrier();
    // ---- phase 3: quadrant (kk1, ih1); stage B-half1
    if (more) STAGEH(Bblk + (size_t)128 * ldb, ldb, Bnx + 8192, d0n);
    QUAD(1, 1, Acur, Bcur);
    __builtin_amdgcn_s_barrier();
  }
#undef STAGEH
#undef QUAD

  // epilogue: C/D layout col = lane&15, row = (lane>>4)*4 + reg
  if (MODE == 0) {
#pragma unroll
    for (int j = 0; j < 4; ++j) {
      const int col = n0 + wc * 64 + 16 * j + lq;
      if (col >= ncols) continue;
#pragma unroll
      for (int i = 0; i < 8; ++i)
#pragma unroll
        for (int r = 0; r < 4; ++r) {
          const int row = m0 + wr * 128 + 16 * i + 4 * lh + r;
          outF[(size_t)zb * oStride + (size_t)row * ldo + col] = acc[i][j][r];
        }
    }
  } else if (MODE == 3) {
#pragma unroll
    for (int j = 0; j < 4; ++j) {
      const int col = n0 + wc * 64 + 16 * j + lq;
#pragma unroll
      for (int i = 0; i < 8; ++i)
#pragma unroll
        for (int r = 0; r < 4; ++r) {
          const int row = m0 + wr * 128 + 16 * i + 4 * lh + r;
          outB[(size_t)zb * oStride + ((size_t)row << 10) + col] = f2bf(acc[i][j][r]);
        }
    }
  } else {  // MODE 1: QKV split epilogue
#pragma unroll
    for (int j = 0; j < 4; ++j) {
      const int col = n0 + wc * 64 + 16 * j + lq;
      if (col >= 2880) continue;
      const int seg = (col >= 1920) ? 2 : (col >= 960 ? 1 : 0);
      const int dcol = col - seg * 960;
      const float bv = bias[col];
#pragma unroll
      for (int i = 0; i < 8; ++i)
#pragma unroll
        for (int r = 0; r < 4; ++r) {
          const int row = m0 + wr * 128 + 16 * i + 4 * lh + r;  // b*1024+s
          const unsigned short v = f2bf(acc[i][j][r] + bv);
          if (seg == 0) outQ[(size_t)row * 960 + dcol] = v;
          else if (seg == 1) outK[(size_t)row * 960 + dcol] = v;
          else outV[((size_t)(row >> 10) << 20) + ((size_t)dcol << 10) + (row & 1023)] = v;
        }
    }
  }
}

// ---------------------------------------------------------------------------
// In-place masked softmax over S[32][1024][1024] bf16 rows. Wave per row,
// 4 rows/block. mask==0 -> weight 0 (matches reference's -1e9 + softmax).
// ---------------------------------------------------------------------------
__global__ __launch_bounds__(256) void softmax_rows(
    unsigned short* __restrict__ S, const int* __restrict__ mask) {
  const int row = blockIdx.x * 4 + (threadIdx.x >> 6);
  const int l = threadIdx.x & 63;
  const int b = row >> 10;
  unsigned short* rp = S + ((size_t)row << 10);
  float v[16];
#pragma unroll
  for (int c = 0; c < 2; ++c) {
    const int k0 = c * 512 + l * 8;
    bf16x8 d = *(const bf16x8*)(rp + k0);
    const int4 m0 = *(const int4*)(mask + b * 1024 + k0);
    const int4 m1 = *(const int4*)(mask + b * 1024 + k0 + 4);
    v[c * 8 + 0] = m0.x ? bf2f((unsigned short)d[0]) : -1e30f;
    v[c * 8 + 1] = m0.y ? bf2f((unsigned short)d[1]) : -1e30f;
    v[c * 8 + 2] = m0.z ? bf2f((unsigned short)d[2]) : -1e30f;
    v[c * 8 + 3] = m0.w ? bf2f((unsigned short)d[3]) : -1e30f;
    v[c * 8 + 4] = m1.x ? bf2f((unsigned short)d[4]) : -1e30f;
    v[c * 8 + 5] = m1.y ? bf2f((unsigned short)d[5]) : -1e30f;
    v[c * 8 + 6] = m1.z ? bf2f((unsigned short)d[6]) : -1e30f;
    v[c * 8 + 7] = m1.w ? bf2f((unsigned short)d[7]) : -1e30f;
  }
  float m = v[0];
#pragma unroll
  for (int i = 1; i < 16; ++i) m = fmaxf(m, v[i]);
#pragma unroll
  for (int o = 1; o < 64; o <<= 1) m = fmaxf(m, __shfl_xor(m, o));
  float s = 0.f;
#pragma unroll
  for (int i = 0; i < 16; ++i) {
    v[i] = __expf(v[i] - m);
    s += v[i];
  }
#pragma unroll
  for (int o = 1; o < 64; o <<= 1) s += __shfl_xor(s, o);
  const float inv = 1.0f / s;
#pragma unroll
  for (int c = 0; c < 2; ++c) {
    bf16x8 o;
#pragma unroll
    for (int i = 0; i < 8; ++i) o[i] = (short)f2bf(v[c * 8 + i] * inv);
    *(bf16x8*)(rp + c * 512 + l * 8) = o;
  }
}

// ---------------------------------------------------------------------------
// h = ctx + x; LayerNorm(h)*g+b; pooled[b,d] += y for masked rows (atomics).
// ---------------------------------------------------------------------------
__global__ __launch_bounds__(256) void ln_pool(
    const float* __restrict__ ctx, const float* __restrict__ x, const int* __restrict__ mask,
    const float* __restrict__ g, const float* __restrict__ bta, float* __restrict__ pooled) {
  const int b = blockIdx.y, chunk = blockIdx.x;
  const int w = threadIdx.x >> 6, l = threadIdx.x & 63;
  f32x4 gc[4], bc[4];
#pragma unroll
  for (int c = 0; c < 4; ++c) {
    const int i4 = c * 64 + l;
    if (i4 < 240) {
      gc[c] = *(const f32x4*)(g + i4 * 4);
      bc[c] = *(const f32x4*)(bta + i4 * 4);
    }
  }
  f32x4 accp[4] = {};
  for (int rr = 0; rr < 8; ++rr) {
    const int s = chunk * 32 + w * 8 + rr;
    if (mask[b * 1024 + s] == 0) continue;
    const size_t base = ((size_t)b * 1024 + s) * 960;
    f32x4 h[4];
    float part = 0.f;
#pragma unroll
    for (int c = 0; c < 4; ++c) {
      const int i4 = c * 64 + l;
      if (i4 < 240) {
        f32x4 cv = *(const f32x4*)(ctx + base + (size_t)i4 * 4);
        f32x4 xv = *(const f32x4*)(x + base + (size_t)i4 * 4);
        h[c] = cv + xv;
        part += h[c][0] + h[c][1] + h[c][2] + h[c][3];
      } else {
        h[c] = 0;
      }
    }
#pragma unroll
    for (int o = 1; o < 64; o <<= 1) part += __shfl_xor(part, o);
    const float mu = part * (1.0f / 960.0f);
    float p2 = 0.f;
#pragma unroll
    for (int c = 0; c < 4; ++c) {
      if (c * 64 + l < 240) {
#pragma unroll
        for (int k2 = 0; k2 < 4; ++k2) {
          const float d = h[c][k2] - mu;
          p2 += d * d;
        }
      }
    }
#pragma unroll
    for (int o = 1; o < 64; o <<= 1) p2 += __shfl_xor(p2, o);
    const float rs = rsqrtf(p2 * (1.0f / 960.0f) + 1e-5f);
#pragma unroll
    for (int c = 0; c < 4; ++c) {
      if (c * 64 + l < 240) {
#pragma unroll
        for (int k2 = 0; k2 < 4; ++k2)
          accp[c][k2] += (h[c][k2] - mu) * rs * gc[c][k2] + bc[c][k2];
      }
    }
  }
#pragma unroll
  for (int c = 0; c < 4; ++c) {
    const int i4 = c * 64 + l;
    if (i4 < 240) {
#pragma unroll
      for (int k2 = 0; k2 < 4; ++k2) atomicAdd(&pooled[b * 960 + i4 * 4 + k2], accp[c][k2]);
    }
  }
}

// ---------------------------------------------------------------------------
// pooled/count -> 960-512-256-128-10 MLP fp32. One block per batch row.
// ---------------------------------------------------------------------------
__global__ __launch_bounds__(256) void mlp_head(
    const float* __restrict__ pooled, const int* __restrict__ mask,
    const float* __restrict__ W1, const float* __restrict__ b1,
    const float* __restrict__ W2, const float* __restrict__ b2,
    const float* __restrict__ W3, const float* __restrict__ b3,
    const float* __restrict__ W4, const float* __restrict__ b4, float* __restrict__ out) {
  __shared__ float h0[960], h1[512], h2[256], h3[128];
  __shared__ float csh[4];
  const int b = blockIdx.x, t = threadIdx.x;
  int cnt = 0;
  for (int s = t; s < 1024; s += 256) cnt += (mask[b * 1024 + s] != 0) ? 1 : 0;
#pragma unroll
  for (int o = 1; o < 64; o <<= 1) cnt += __shfl_xor(cnt, o);
  if ((t & 63) == 0) csh[t >> 6] = (float)cnt;
  __syncthreads();
  const float inv = 1.0f / fmaxf(csh[0] + csh[1] + csh[2] + csh[3], 1e-9f);
  for (int d = t; d < 960; d += 256) h0[d] = pooled[b * 960 + d] * inv;
  __syncthreads();
  for (int o = t; o < 512; o += 256) {
    float a = b1[o];
    const float* wr = W1 + (size_t)o * 960;
    for (int k = 0; k < 960; k += 4) {
      f32x4 wv = *(const f32x4*)(wr + k);
      f32x4 hv = *(const f32x4*)(h0 + k);
      a += wv[0] * hv[0] + wv[1] * hv[1] + wv[2] * hv[2] + wv[3] * hv[3];
    }
    h1[o] = fmaxf(a, 0.f);
  }
  __syncthreads();
  {
    float a = b2[t];
    const float* wr = W2 + (size_t)t * 512;
    for (int k = 0; k < 512; k += 4) {
      f32x4 wv = *(const f32x4*)(wr + k);
      f32x4 hv = *(const f32x4*)(h1 + k);
      a += wv[0] * hv[0] + wv[1] * hv[1] + wv[2] * hv[2] + wv[3] * hv[3];
    }
    h2[t] = fmaxf(a, 0.f);
  }
  __syncthreads();
  if (t < 128) {
    float a = b3[t];
    const float* wr = W3 + (size_t)t * 256;
    for (int k = 0; k < 256; k += 4) {
      f32x4 wv = *(const f32x4*)(wr + k);
      f32x4 hv = *(const f32x4*)(h2 + k);
      a += wv[0] * hv[0] + wv[1] * hv[1] + wv[2] * hv[2] + wv[3] * hv[3];
    }
    h3[t] = fmaxf(a, 0.f);
  }
  __syncthreads();
  if (t < 10) {
    float a = b4[t];
    const float* wr = W4 + (size_t)t * 128;
    for (int k = 0; k < 128; ++k) a += wr[k] * h3[k];
    out[b * 10 + t] = a;
  }
}

// ---------------------------------------------------------------------------
// Workspace (bytes):
//   [0,          67108864)  xb bf16 [32768][1024] -> S/P bf16 [32][1024][1024]
//   [67108864,  130023424)  Qb bf16 [32768][960]  \ after softmax: ctx f32
//   [130023424, 192937984)  Kb bf16 [32768][960]  /   [32768][960] (125829120B)
//   [192937984, 260046848)  Vt bf16 [32][1024][1024] (d rows 960+ garbage)
//   [260046848, 266338304)  Wqkv bf16 [3072][1024]
//   [266338304, 266349824)  biasQKV f32 [2880]
//   [266349824, 266472704)  pooled f32 [32][960]
// ---------------------------------------------------------------------------
extern "C" void kernel_launch(void* const* d_in, const int* in_sizes, int n_in,
                              void* d_out, int out_size, void* d_ws, size_t ws_size,
                              hipStream_t stream) {
  (void)in_sizes; (void)n_in; (void)out_size; (void)ws_size;
  const float* x    = (const float*)d_in[0];
  const int*   mask = (const int*)d_in[1];
  const float* Wq   = (const float*)d_in[2];
  const float* bq   = (const float*)d_in[3];
  const float* Wk   = (const float*)d_in[4];
  const float* bk   = (const float*)d_in[5];
  const float* Wv   = (const float*)d_in[6];
  const float* bv   = (const float*)d_in[7];
  const float* lng  = (const float*)d_in[8];
  const float* lnb  = (const float*)d_in[9];
  const float* W1   = (const float*)d_in[10];
  const float* b1   = (const float*)d_in[11];
  const float* W2   = (const float*)d_in[12];
  const float* b2   = (const float*)d_in[13];
  const float* W3   = (const float*)d_in[14];
  const float* b3   = (const float*)d_in[15];
  const float* W4   = (const float*)d_in[16];
  const float* b4   = (const float*)d_in[17];
  float* out = (float*)d_out;

  char* ws = (char*)d_ws;
  unsigned short* xb     = (unsigned short*)(ws);
  unsigned short* S      = (unsigned short*)(ws);            // over dead xb
  unsigned short* Qb     = (unsigned short*)(ws + 67108864);
  unsigned short* Kb     = (unsigned short*)(ws + 130023424);
  float*          ctx    = (float*)(ws + 67108864);          // over dead Qb+Kb
  unsigned short* Vt     = (unsigned short*)(ws + 192937984);
  unsigned short* Wqkv   = (unsigned short*)(ws + 260046848);
  float*          biasQ  = (float*)(ws + 266338304);
  float*          pooled = (float*)(ws + 266349824);

  const float scaleQ = 0.0322748612183951f;  // 1/sqrt(960)

  cast_wqkv<<<2880, 256, 0, stream>>>(Wq, Wk, Wv, bq, bk, bv, Wqkv, biasQ, scaleQ);
  cast_x<<<8192, 256, 0, stream>>>(x, xb);

  // fused QKV: [32768 x 2880] = xb[32768x1024] . Wqkv^T; writes Qb, Kb, Vt(T)
  gemm256<1><<<128 * 12, 512, 0, stream>>>(
      xb, Wqkv, 1024, 1024, biasQ, nullptr, nullptr, Qb, Kb, Vt,
      128, 12, 16, 2880, 0, 0, 0, 0);

  // scores: S[b] = Qb[b] . Kb[b]^T  (M=N=1024, K=960), bf16 out over dead xb
  gemm256<3><<<4 * 4 * 32, 512, 0, stream>>>(
      Qb, Kb, 960, 960, nullptr, nullptr, S, nullptr, nullptr, nullptr,
      4, 4, 15, 1024, 1024, (size_t)983040, (size_t)983040, (size_t)1048576);

  softmax_rows<<<8192, 256, 0, stream>>>(S, mask);

  // context[b] = P[b] . Vt[b]^T : M=1024, N=960, K=1024, f32 out over Qb+Kb
  gemm256<0><<<4 * 4 * 32, 512, 0, stream>>>(
      S, Vt, 1024, 1024, nullptr, ctx, nullptr, nullptr, nullptr, nullptr,
      4, 4, 16, 960, 960, (size_t)1048576, (size_t)1048576, (size_t)983040);

  hipMemsetAsync(pooled, 0, 32 * 960 * 4, stream);
  ln_pool<<<dim3(32, 32), 256, 0, stream>>>(ctx, x, mask, lng, lnb, pooled);
  mlp_head<<<32, 256, 0, stream>>>(pooled, mask, W1, b1, W2, b2, W3, b3, W4, b4, out);
}

// Round 5
// 722.276 us; speedup vs baseline: 1.1704x; 1.1704x over previous
//
#include <hip/hip_runtime.h>

// ---------------------------------------------------------------------------
// DeepProteinClassifier: x[32,1024,960] fp32, mask[32,1024] i32 ->
//   fused QKV proj -> fused attention (scores+softmax) -> PV GEMM ->
//   +x, LN -> masked mean pool -> MLP -> [32,10] f32
// GEMMs: 128x128 tile, BK=64, double-buffered LDS (64KB -> 2 blocks/CU),
// counted-vmcnt pipeline (never drains prefetch at the barrier).
// ---------------------------------------------------------------------------

#define DEVINL __device__ __forceinline__

typedef __attribute__((ext_vector_type(8))) short bf16x8;
typedef __attribute__((ext_vector_type(4))) float f32x4;
typedef __attribute__((ext_vector_type(4))) unsigned short u16x4;

DEVINL unsigned short f2bf(float f) {
  unsigned int u = __float_as_uint(f);
  u += 0x7FFFu + ((u >> 16) & 1u);  // round-to-nearest-even
  return (unsigned short)(u >> 16);
}

DEVINL void gload_lds16(const void* g, void* l) {
  __builtin_amdgcn_global_load_lds((const __attribute__((address_space(1))) unsigned int*)g,
                                   (__attribute__((address_space(3))) unsigned int*)l,
                                   16, 0, 0);
}

#define MFMA16(a, b, c) __builtin_amdgcn_mfma_f32_16x16x32_bf16((a), (b), (c), 0, 0, 0)

// ---------------------------------------------------------------------------
// Build Wqkv [3072][1024] bf16 (rows 0..959 Wq*scale, 960..1919 Wk,
// 1920..2879 Wv; cols 960..1023 zero) and biasQKV[2880] f32.
// ---------------------------------------------------------------------------
__global__ __launch_bounds__(256) void cast_wqkv(
    const float* __restrict__ Wq, const float* __restrict__ Wk, const float* __restrict__ Wv,
    const float* __restrict__ bq, const float* __restrict__ bk, const float* __restrict__ bv,
    unsigned short* __restrict__ Wqkv, float* __restrict__ biasQ, float scaleQ) {
  const int r = blockIdx.x, t = threadIdx.x;
  const int seg = (r >= 1920) ? 2 : (r >= 960 ? 1 : 0);
  const int sr = r - seg * 960;
  const float* W = (seg == 0) ? Wq : (seg == 1) ? Wk : Wv;
  const float sc = (seg == 0) ? scaleQ : 1.0f;
  if (t < 240) {
    f32x4 v = *(const f32x4*)(W + (size_t)sr * 960 + t * 4);
    u16x4 o;
    o[0] = f2bf(v[0] * sc); o[1] = f2bf(v[1] * sc);
    o[2] = f2bf(v[2] * sc); o[3] = f2bf(v[3] * sc);
    *(u16x4*)(Wqkv + (size_t)r * 1024 + t * 4) = o;
  } else {
    u16x4 z = {};
    *(u16x4*)(Wqkv + (size_t)r * 1024 + 960 + (t - 240) * 4) = z;
  }
  if (t == 0) {
    const float* bb = (seg == 0) ? bq : (seg == 1) ? bk : bv;
    biasQ[r] = bb[sr] * sc;
  }
}

// ---------------------------------------------------------------------------
// cast x [32768][960] f32 -> xb [32768][1024] bf16 (cols 960.. zero).
// ---------------------------------------------------------------------------
__global__ __launch_bounds__(256) void cast_x(
    const float* __restrict__ x, unsigned short* __restrict__ xb) {
  const int row = blockIdx.x * 4 + (threadIdx.x >> 6);
  const int l = threadIdx.x & 63;
  unsigned short* o = xb + (size_t)row * 1024 + l * 16;
  if (l < 60) {
    const float* g = x + (size_t)row * 960 + l * 16;
    f32x4 v0 = *(const f32x4*)(g);
    f32x4 v1 = *(const f32x4*)(g + 4);
    f32x4 v2 = *(const f32x4*)(g + 8);
    f32x4 v3 = *(const f32x4*)(g + 12);
    bf16x8 o0, o1;
    o0[0] = (short)f2bf(v0[0]); o0[1] = (short)f2bf(v0[1]);
    o0[2] = (short)f2bf(v0[2]); o0[3] = (short)f2bf(v0[3]);
    o0[4] = (short)f2bf(v1[0]); o0[5] = (short)f2bf(v1[1]);
    o0[6] = (short)f2bf(v1[2]); o0[7] = (short)f2bf(v1[3]);
    o1[0] = (short)f2bf(v2[0]); o1[1] = (short)f2bf(v2[1]);
    o1[2] = (short)f2bf(v2[2]); o1[3] = (short)f2bf(v2[3]);
    o1[4] = (short)f2bf(v3[0]); o1[5] = (short)f2bf(v3[1]);
    o1[6] = (short)f2bf(v3[2]); o1[7] = (short)f2bf(v3[3]);
    *(bf16x8*)(o) = o0;
    *(bf16x8*)(o + 8) = o1;
  } else {
    bf16x8 z = {};
    *(bf16x8*)(o) = z;
    *(bf16x8*)(o + 8) = z;
  }
}

// ---------------------------------------------------------------------------
// 128x128 NT GEMM, BK=64, 4 waves (2x2), 64x64 out/wave, dbuf LDS (64KB ->
// 2 blocks/CU). Counted-vmcnt: STAGE(t+1) [8 gloads/thread], vmcnt(8),
// s_barrier, compute(t) [16 ds_read_b128 + 32 MFMA], s_barrier.
// Source-side (row&7) 16B-slot XOR swizzle (measured 0 bank conflicts).
// MODE 0: f32 out.  MODE 1: QKV epilogue (bf16 +bias -> Qb/Kb/Vt-transposed).
// XCD-chunked flat-grid swizzle (nwg % 8 == 0), n-tile fastest.
// ---------------------------------------------------------------------------
template <int MODE>
__global__ __launch_bounds__(256, 2) void gemm128(
    const unsigned short* __restrict__ Ap, const unsigned short* __restrict__ Bp,
    int lda, int ldb, const float* __restrict__ bias,
    float* __restrict__ outF, unsigned short* __restrict__ outQ,
    unsigned short* __restrict__ outK, unsigned short* __restrict__ outV,
    int mTiles, int nTiles, int nkt, int ncols, int ldo,
    size_t aStride, size_t bStride, size_t oStride) {
  __shared__ unsigned short As[2][128 * 64];
  __shared__ unsigned short Bs[2][128 * 64];
  const int t = threadIdx.x, l = t & 63, w = t >> 6;
  const int wr = w >> 1, wc = w & 1;
  const int lq = l & 15, lh = l >> 4;

  const int nwg = (int)gridDim.x;
  const int flat = (int)blockIdx.x;
  const int swz = (flat & 7) * (nwg >> 3) + (flat >> 3);
  const int pt = mTiles * nTiles;
  const int zb = swz / pt;
  const int rm = swz - zb * pt;
  const int mi = rm / nTiles;
  const int m0 = mi * 128;
  const int n0 = (rm - mi * nTiles) * 128;

  const unsigned short* A = Ap + (size_t)zb * aStride + (size_t)m0 * lda;
  const unsigned short* B = Bp + (size_t)zb * bStride + (size_t)n0 * ldb;

#define STAGEG(D0, BB)                                                        \
  {                                                                           \
    _Pragma("unroll") for (int q_ = 0; q_ < 4; ++q_) {                        \
      const int r_ = q_ * 32 + w * 8 + (l >> 3);                              \
      const int sg_ = (l & 7) ^ (r_ & 7);                                     \
      gload_lds16(A + (size_t)r_ * lda + (D0) + sg_ * 8,                      \
                  (char*)&As[BB][(size_t)(q_ * 32 + w * 8) * 64]);            \
      gload_lds16(B + (size_t)r_ * ldb + (D0) + sg_ * 8,                      \
                  (char*)&Bs[BB][(size_t)(q_ * 32 + w * 8) * 64]);            \
    }                                                                         \
  }

  f32x4 acc[4][4] = {};
  STAGEG(0, 0);
  int buf = 0;
  for (int kt = 0; kt < nkt; ++kt) {
    if (kt + 1 < nkt) {
      STAGEG((kt + 1) * 64, buf ^ 1);
      asm volatile("s_waitcnt vmcnt(8)" ::: "memory");   // tile kt landed; kt+1 in flight
    } else {
      asm volatile("s_waitcnt vmcnt(0)" ::: "memory");
    }
    __builtin_amdgcn_sched_barrier(0);
    __builtin_amdgcn_s_barrier();
    bf16x8 aF[2][4], bF[2][4];
#pragma unroll
    for (int h = 0; h < 2; ++h)
#pragma unroll
      for (int i = 0; i < 4; ++i) {
        const int rowA = 64 * wr + 16 * i + lq;
        aF[h][i] = *(const bf16x8*)&As[buf][(size_t)rowA * 64 +
                                           (size_t)(((h << 2) | lh) ^ (rowA & 7)) * 8];
        const int rowB = 64 * wc + 16 * i + lq;
        bF[h][i] = *(const bf16x8*)&Bs[buf][(size_t)rowB * 64 +
                                           (size_t)(((h << 2) | lh) ^ (rowB & 7)) * 8];
      }
#pragma unroll
    for (int h = 0; h < 2; ++h)
#pragma unroll
      for (int i = 0; i < 4; ++i)
#pragma unroll
        for (int j = 0; j < 4; ++j) acc[i][j] = MFMA16(aF[h][i], bF[h][j], acc[i][j]);
    __builtin_amdgcn_s_barrier();
    buf ^= 1;
  }
#undef STAGEG

  // epilogue: C/D layout col = lane&15, row = (lane>>4)*4 + reg
  if (MODE == 0) {
#pragma unroll
    for (int j = 0; j < 4; ++j) {
      const int col = n0 + 64 * wc + 16 * j + lq;
      if (col >= ncols) continue;
#pragma unroll
      for (int i = 0; i < 4; ++i)
#pragma unroll
        for (int r = 0; r < 4; ++r) {
          const int row = m0 + 64 * wr + 16 * i + 4 * lh + r;
          outF[(size_t)zb * oStride + (size_t)row * ldo + col] = acc[i][j][r];
        }
    }
  } else {  // MODE 1: QKV split epilogue
#pragma unroll
    for (int j = 0; j < 4; ++j) {
      const int col = n0 + 64 * wc + 16 * j + lq;
      if (col >= ncols) continue;
      const int seg = (col >= 1920) ? 2 : (col >= 960 ? 1 : 0);
      const int dcol = col - seg * 960;
      const float bv = bias[col];
#pragma unroll
      for (int i = 0; i < 4; ++i)
#pragma unroll
        for (int r = 0; r < 4; ++r) {
          const int row = m0 + 64 * wr + 16 * i + 4 * lh + r;  // b*1024+s
          const unsigned short v = f2bf(acc[i][j][r] + bv);
          if (seg == 0) outQ[(size_t)row * 960 + dcol] = v;
          else if (seg == 1) outK[(size_t)row * 960 + dcol] = v;
          else outV[((size_t)(row >> 10) << 20) + ((size_t)dcol << 10) + (row & 1023)] = v;
        }
    }
  }
}

// ---------------------------------------------------------------------------
// Fused scores + masked softmax (counted-vmcnt pipeline, from round 3).
// Block = 64 q-rows x full 1024 k for one b; 8 waves, wave w owns k-cols
// [128w,128w+128). K slab (1024x32) + Q slab (64x32) double-buffered in LDS.
// All 8 waves issue exactly 9 gloads per stage so vmcnt(9) is wave-uniform.
// ---------------------------------------------------------------------------
__global__ __launch_bounds__(512, 2) void attn_softmax(
    const unsigned short* __restrict__ Qb, const unsigned short* __restrict__ Kb,
    const int* __restrict__ mask, unsigned short* __restrict__ P) {
  __shared__ unsigned short Ks[2][1024 * 32];
  __shared__ unsigned short Qs[2][64 * 32];
  __shared__ float red[2][8][64];
  const int t = threadIdx.x, l = t & 63, w = t >> 6;
  const int flat = blockIdx.x;
  const int b = (flat & 7) * 4 + ((flat >> 3) >> 4);
  const int q0 = ((flat >> 3) & 15) * 64;
  const int lq = l & 15, lh = l >> 4;
  const size_t kbase = (size_t)b * 1024 * 960;
  const size_t qbase = ((size_t)b * 1024 + q0) * 960;
  const int lr = l >> 2, sg0 = l & 3;  // 16 rows x 4 slots(16B) per 1KB issue

#define STAGE(kkv, bufv)                                                      \
  {                                                                           \
    const int d0_ = (kkv) * 32;                                               \
    _Pragma("unroll") for (int i_ = 0; i_ < 8; ++i_) {                        \
      const int br_ = i_ * 128 + w * 16;                                      \
      const int kr_ = br_ + lr;                                               \
      const int sg_ = sg0 ^ ((kr_ >> 1) & 3);                                 \
      gload_lds16(Kb + kbase + (size_t)kr_ * 960 + d0_ + sg_ * 8,             \
                  (char*)Ks[(bufv)] + (size_t)br_ * 64);                      \
    }                                                                         \
    {                                                                         \
      const int qw_ = w & 3;                                                  \
      const int qr_ = qw_ * 16 + lr;                                          \
      const int sg_ = sg0 ^ ((qr_ >> 1) & 3);                                 \
      gload_lds16(Qb + qbase + (size_t)qr_ * 960 + d0_ + sg_ * 8,             \
                  (char*)Qs[(bufv)] + (size_t)(qw_ * 16) * 64);               \
    }                                                                         \
  }

  f32x4 acc[4][8] = {};
  STAGE(0, 0);
  int buf = 0;
  for (int kk = 0; kk < 30; ++kk) {
    if (kk < 29) {
      STAGE(kk + 1, buf ^ 1);
      asm volatile("s_waitcnt vmcnt(9)" ::: "memory");
    } else {
      asm volatile("s_waitcnt vmcnt(0)" ::: "memory");
    }
    __builtin_amdgcn_sched_barrier(0);
    __builtin_amdgcn_s_barrier();
    bf16x8 aF[4], bF[8];
#pragma unroll
    for (int i = 0; i < 4; ++i) {
      const int qr = 16 * i + lq;
      aF[i] = *(const bf16x8*)(Qs[buf] + qr * 32 + (lh ^ ((qr >> 1) & 3)) * 8);
    }
#pragma unroll
    for (int j = 0; j < 8; ++j) {
      const int kr = 128 * w + 16 * j + lq;
      bF[j] = *(const bf16x8*)(Ks[buf] + kr * 32 + (lh ^ ((kr >> 1) & 3)) * 8);
    }
#pragma unroll
    for (int i = 0; i < 4; ++i)
#pragma unroll
      for (int j = 0; j < 8; ++j) acc[i][j] = MFMA16(aF[i], bF[j], acc[i][j]);
    __builtin_amdgcn_s_barrier();
    buf ^= 1;
  }
#undef STAGE

  // mask -> -1e9
#pragma unroll
  for (int j = 0; j < 8; ++j) {
    const int k = 128 * w + 16 * j + lq;
    if (mask[b * 1024 + k] == 0) {
#pragma unroll
      for (int i = 0; i < 4; ++i)
#pragma unroll
        for (int r = 0; r < 4; ++r) acc[i][j][r] = -1e9f;
    }
  }

  // row max: over j in-lane, over 16 col-lanes via shfl, over 8 waves via LDS
  float rmax[4][4];
#pragma unroll
  for (int i = 0; i < 4; ++i)
#pragma unroll
    for (int r = 0; r < 4; ++r) {
      float m = acc[i][0][r];
#pragma unroll
      for (int j = 1; j < 8; ++j) m = fmaxf(m, acc[i][j][r]);
      m = fmaxf(m, __shfl_xor(m, 1));
      m = fmaxf(m, __shfl_xor(m, 2));
      m = fmaxf(m, __shfl_xor(m, 4));
      m = fmaxf(m, __shfl_xor(m, 8));
      rmax[i][r] = m;
    }
  if (lq == 0) {
#pragma unroll
    for (int i = 0; i < 4; ++i)
#pragma unroll
      for (int r = 0; r < 4; ++r) red[0][w][16 * i + 4 * lh + r] = rmax[i][r];
  }
  __syncthreads();
#pragma unroll
  for (int i = 0; i < 4; ++i)
#pragma unroll
    for (int r = 0; r < 4; ++r) {
      const int rowi = 16 * i + 4 * lh + r;
      float m = red[0][0][rowi];
#pragma unroll
      for (int w2 = 1; w2 < 8; ++w2) m = fmaxf(m, red[0][w2][rowi]);
      rmax[i][r] = m;
    }

  float rsum[4][4];
#pragma unroll
  for (int i = 0; i < 4; ++i)
#pragma unroll
    for (int r = 0; r < 4; ++r) {
      float s = 0.f;
#pragma unroll
      for (int j = 0; j < 8; ++j) {
        const float e = __expf(acc[i][j][r] - rmax[i][r]);
        acc[i][j][r] = e;
        s += e;
      }
      s += __shfl_xor(s, 1); s += __shfl_xor(s, 2);
      s += __shfl_xor(s, 4); s += __shfl_xor(s, 8);
      rsum[i][r] = s;
    }
  if (lq == 0) {
#pragma unroll
    for (int i = 0; i < 4; ++i)
#pragma unroll
      for (int r = 0; r < 4; ++r) red[1][w][16 * i + 4 * lh + r] = rsum[i][r];
  }
  __syncthreads();

  const size_t pb = ((size_t)b << 20) + (size_t)q0 * 1024;
#pragma unroll
  for (int i = 0; i < 4; ++i)
#pragma unroll
    for (int r = 0; r < 4; ++r) {
      const int rowi = 16 * i + 4 * lh + r;
      float s = 0.f;
#pragma unroll
      for (int w2 = 0; w2 < 8; ++w2) s += red[1][w2][rowi];
      const float inv = 1.0f / s;
#pragma unroll
      for (int j = 0; j < 8; ++j) {
        const int col = 128 * w + 16 * j + lq;
        P[pb + (size_t)rowi * 1024 + col] = f2bf(acc[i][j][r] * inv);
      }
    }
}

// ---------------------------------------------------------------------------
// h = ctx + x; LayerNorm(h)*g+b; pooled[b,d] += y for masked rows (atomics).
// ---------------------------------------------------------------------------
__global__ __launch_bounds__(256) void ln_pool(
    const float* __restrict__ ctx, const float* __restrict__ x, const int* __restrict__ mask,
    const float* __restrict__ g, const float* __restrict__ bta, float* __restrict__ pooled) {
  const int b = blockIdx.y, chunk = blockIdx.x;
  const int w = threadIdx.x >> 6, l = threadIdx.x & 63;
  f32x4 gc[4], bc[4];
#pragma unroll
  for (int c = 0; c < 4; ++c) {
    const int i4 = c * 64 + l;
    if (i4 < 240) {
      gc[c] = *(const f32x4*)(g + i4 * 4);
      bc[c] = *(const f32x4*)(bta + i4 * 4);
    }
  }
  f32x4 accp[4] = {};
  for (int rr = 0; rr < 8; ++rr) {
    const int s = chunk * 32 + w * 8 + rr;
    if (mask[b * 1024 + s] == 0) continue;
    const size_t base = ((size_t)b * 1024 + s) * 960;
    f32x4 h[4];
    float part = 0.f;
#pragma unroll
    for (int c = 0; c < 4; ++c) {
      const int i4 = c * 64 + l;
      if (i4 < 240) {
        f32x4 cv = *(const f32x4*)(ctx + base + (size_t)i4 * 4);
        f32x4 xv = *(const f32x4*)(x + base + (size_t)i4 * 4);
        h[c] = cv + xv;
        part += h[c][0] + h[c][1] + h[c][2] + h[c][3];
      } else {
        h[c] = 0;
      }
    }
#pragma unroll
    for (int o = 1; o < 64; o <<= 1) part += __shfl_xor(part, o);
    const float mu = part * (1.0f / 960.0f);
    float p2 = 0.f;
#pragma unroll
    for (int c = 0; c < 4; ++c) {
      if (c * 64 + l < 240) {
#pragma unroll
        for (int k2 = 0; k2 < 4; ++k2) {
          const float d = h[c][k2] - mu;
          p2 += d * d;
        }
      }
    }
#pragma unroll
    for (int o = 1; o < 64; o <<= 1) p2 += __shfl_xor(p2, o);
    const float rs = rsqrtf(p2 * (1.0f / 960.0f) + 1e-5f);
#pragma unroll
    for (int c = 0; c < 4; ++c) {
      if (c * 64 + l < 240) {
#pragma unroll
        for (int k2 = 0; k2 < 4; ++k2)
          accp[c][k2] += (h[c][k2] - mu) * rs * gc[c][k2] + bc[c][k2];
      }
    }
  }
#pragma unroll
  for (int c = 0; c < 4; ++c) {
    const int i4 = c * 64 + l;
    if (i4 < 240) {
#pragma unroll
      for (int k2 = 0; k2 < 4; ++k2) atomicAdd(&pooled[b * 960 + i4 * 4 + k2], accp[c][k2]);
    }
  }
}

// ---------------------------------------------------------------------------
// pooled/count -> 960-512-256-128-10 MLP fp32. One block per batch row.
// ---------------------------------------------------------------------------
__global__ __launch_bounds__(256) void mlp_head(
    const float* __restrict__ pooled, const int* __restrict__ mask,
    const float* __restrict__ W1, const float* __restrict__ b1,
    const float* __restrict__ W2, const float* __restrict__ b2,
    const float* __restrict__ W3, const float* __restrict__ b3,
    const float* __restrict__ W4, const float* __restrict__ b4, float* __restrict__ out) {
  __shared__ float h0[960], h1[512], h2[256], h3[128];
  __shared__ float csh[4];
  const int b = blockIdx.x, t = threadIdx.x;
  int cnt = 0;
  for (int s = t; s < 1024; s += 256) cnt += (mask[b * 1024 + s] != 0) ? 1 : 0;
#pragma unroll
  for (int o = 1; o < 64; o <<= 1) cnt += __shfl_xor(cnt, o);
  if ((t & 63) == 0) csh[t >> 6] = (float)cnt;
  __syncthreads();
  const float inv = 1.0f / fmaxf(csh[0] + csh[1] + csh[2] + csh[3], 1e-9f);
  for (int d = t; d < 960; d += 256) h0[d] = pooled[b * 960 + d] * inv;
  __syncthreads();
  for (int o = t; o < 512; o += 256) {
    float a = b1[o];
    const float* wr = W1 + (size_t)o * 960;
    for (int k = 0; k < 960; k += 4) {
      f32x4 wv = *(const f32x4*)(wr + k);
      f32x4 hv = *(const f32x4*)(h0 + k);
      a += wv[0] * hv[0] + wv[1] * hv[1] + wv[2] * hv[2] + wv[3] * hv[3];
    }
    h1[o] = fmaxf(a, 0.f);
  }
  __syncthreads();
  {
    float a = b2[t];
    const float* wr = W2 + (size_t)t * 512;
    for (int k = 0; k < 512; k += 4) {
      f32x4 wv = *(const f32x4*)(wr + k);
      f32x4 hv = *(const f32x4*)(h1 + k);
      a += wv[0] * hv[0] + wv[1] * hv[1] + wv[2] * hv[2] + wv[3] * hv[3];
    }
    h2[t] = fmaxf(a, 0.f);
  }
  __syncthreads();
  if (t < 128) {
    float a = b3[t];
    const float* wr = W3 + (size_t)t * 256;
    for (int k = 0; k < 256; k += 4) {
      f32x4 wv = *(const f32x4*)(wr + k);
      f32x4 hv = *(const f32x4*)(h2 + k);
      a += wv[0] * hv[0] + wv[1] * hv[1] + wv[2] * hv[2] + wv[3] * hv[3];
    }
    h3[t] = fmaxf(a, 0.f);
  }
  __syncthreads();
  if (t < 10) {
    float a = b4[t];
    const float* wr = W4 + (size_t)t * 128;
    for (int k = 0; k < 128; ++k) a += wr[k] * h3[k];
    out[b * 10 + t] = a;
  }
}

// ---------------------------------------------------------------------------
// Workspace (bytes):
//   [0,          67108864)  xb bf16 [32768][1024] -> P bf16 [32][1024][1024]
//   [67108864,  130023424)  Qb bf16 [32768][960]  \ after attn: ctx f32
//   [130023424, 192937984)  Kb bf16 [32768][960]  /   [32768][960]
//   [192937984, 260046848)  Vt bf16 [32][1024][1024] (d rows 960+ garbage)
//   [260046848, 266338304)  Wqkv bf16 [3072][1024]
//   [266338304, 266349824)  biasQKV f32 [2880]
//   [266349824, 266472704)  pooled f32 [32][960]
// ---------------------------------------------------------------------------
extern "C" void kernel_launch(void* const* d_in, const int* in_sizes, int n_in,
                              void* d_out, int out_size, void* d_ws, size_t ws_size,
                              hipStream_t stream) {
  (void)in_sizes; (void)n_in; (void)out_size; (void)ws_size;
  const float* x    = (const float*)d_in[0];
  const int*   mask = (const int*)d_in[1];
  const float* Wq   = (const float*)d_in[2];
  const float* bq   = (const float*)d_in[3];
  const float* Wk   = (const float*)d_in[4];
  const float* bk   = (const float*)d_in[5];
  const float* Wv   = (const float*)d_in[6];
  const float* bv   = (const float*)d_in[7];
  const float* lng  = (const float*)d_in[8];
  const float* lnb  = (const float*)d_in[9];
  const float* W1   = (const float*)d_in[10];
  const float* b1   = (const float*)d_in[11];
  const float* W2   = (const float*)d_in[12];
  const float* b2   = (const float*)d_in[13];
  const float* W3   = (const float*)d_in[14];
  const float* b3   = (const float*)d_in[15];
  const float* W4   = (const float*)d_in[16];
  const float* b4   = (const float*)d_in[17];
  float* out = (float*)d_out;

  char* ws = (char*)d_ws;
  unsigned short* xb     = (unsigned short*)(ws);
  unsigned short* P      = (unsigned short*)(ws);            // over dead xb
  unsigned short* Qb     = (unsigned short*)(ws + 67108864);
  unsigned short* Kb     = (unsigned short*)(ws + 130023424);
  float*          ctx    = (float*)(ws + 67108864);          // over dead Qb+Kb
  unsigned short* Vt     = (unsigned short*)(ws + 192937984);
  unsigned short* Wqkv   = (unsigned short*)(ws + 260046848);
  float*          biasQ  = (float*)(ws + 266338304);
  float*          pooled = (float*)(ws + 266349824);

  const float scaleQ = 0.0322748612183951f;  // 1/sqrt(960)

  cast_wqkv<<<2880, 256, 0, stream>>>(Wq, Wk, Wv, bq, bk, bv, Wqkv, biasQ, scaleQ);
  cast_x<<<8192, 256, 0, stream>>>(x, xb);

  // fused QKV: [32768 x 2944(2880 used)] = xb . Wqkv^T; writes Qb, Kb, Vt(T)
  gemm128<1><<<256 * 23, 256, 0, stream>>>(
      xb, Wqkv, 1024, 1024, biasQ, nullptr, Qb, Kb, Vt,
      256, 23, 15, 2880, 0, 0, 0, 0);

  attn_softmax<<<512, 512, 0, stream>>>(Qb, Kb, mask, P);

  // context[b] = P[b] . Vt[b]^T : M=1024, N=960, K=1024, f32 out over Qb+Kb
  gemm128<0><<<8 * 8 * 32, 256, 0, stream>>>(
      P, Vt, 1024, 1024, nullptr, ctx, nullptr, nullptr, nullptr,
      8, 8, 16, 960, 960, (size_t)1048576, (size_t)1048576, (size_t)983040);

  hipMemsetAsync(pooled, 0, 32 * 960 * 4, stream);
  ln_pool<<<dim3(32, 32), 256, 0, stream>>>(ctx, x, mask, lng, lnb, pooled);
  mlp_head<<<32, 256, 0, stream>>>(pooled, mask, W1, b1, W2, b2, W3, b3, W4, b4, out);
}